// Round 3
// baseline (1278.598 us; speedup 1.0000x reference)
//
#include <hip/hip_runtime.h>

typedef _Float16 f16;
typedef _Float16 f16x8 __attribute__((ext_vector_type(8)));
typedef float f32x4 __attribute__((ext_vector_type(4)));

#define MFMA16(a, b, c) __builtin_amdgcn_mfma_f32_16x16x32_f16((a), (b), (c), 0, 0, 0)

// ---- Tsit5 coefficients (fp32) ----
#define A21f 0.161f
#define A31f (-0.008480655492356989f)
#define A32f 0.335480655492357f
#define A41f 2.8971530571054935f
#define A42f (-6.359448489975075f)
#define A43f 4.3622954328695815f
#define A51f 5.325864828439257f
#define A52f (-11.748883564062828f)
#define A53f 7.4955393428898365f
#define A54f (-0.09249506636175525f)
#define A61f 5.86145544294642f
#define A62f (-12.92096931784711f)
#define A63f 8.159367898576159f
#define A64f (-0.071584973281401f)
#define A65f (-0.028269050394068383f)
#define B1f 0.09646076681806523f
#define B2f 0.01f
#define B3f 0.4798896504144996f
#define B4f 1.379008574103742f
#define B5f (-3.290069515436081f)
#define B6f 2.324710524099774f
#define C2f 0.161f
#define C3f 0.327f
#define C4f 0.9f
#define C5f 0.9800255409045097f
#define C6f 1.0f

// ---- LDS layout (bytes), pitch-padded (+16B/row) to spread bank blocks ----
// Y  : 16 rows x 128 f16, pitch 272
// Z1 : 16 rows x 256 f16, pitch 528
// Z2 : 16 rows x 256 f16, pitch 528
// X  : 16 rows x  32 f16, pitch  80
// TS : 16 rows x  64 f32 (linear)
// WH : 128 rows x 128 f16, pitch 272
#define PY 272
#define PZ 528
#define PX 80
#define PW 272
#define LDS_Y   0
#define LDS_Z1  4352
#define LDS_Z2  12800
#define LDS_X   21248
#define LDS_TS  22528
#define LDS_WH  26624
#define LDS_TOT 61440

__device__ __forceinline__ int yoff(int row, int bc)  { return LDS_Y  + row * PY + bc; }
__device__ __forceinline__ int z1off(int row, int bc) { return LDS_Z1 + row * PZ + bc; }
__device__ __forceinline__ int z2off(int row, int bc) { return LDS_Z2 + row * PZ + bc; }
__device__ __forceinline__ int xoff(int row, int bc)  { return LDS_X  + row * PX + bc; }
__device__ __forceinline__ int whoff(int row, int bc) { return LDS_WH + row * PW + bc; }

// branch-free fast activations (v_exp + v_rcp)
__device__ __forceinline__ float tanh_fast(float x) {
  return 2.0f * __builtin_amdgcn_rcpf(1.0f + __expf(-2.0f * x)) - 1.0f;
}
__device__ __forceinline__ float siluf(float x) {
  return x * __builtin_amdgcn_rcpf(1.0f + __expf(-x));
}

__global__ __launch_bounds__(512, 2)
void ode_rnn_kernel(const float* __restrict__ ts, const float* __restrict__ Xg,
                    const float* __restrict__ Sg,
                    const float* __restrict__ w0g, const float* __restrict__ b0g,
                    const float* __restrict__ w1g, const float* __restrict__ b1g,
                    const float* __restrict__ w2g, const float* __restrict__ b2g,
                    const float* __restrict__ scaleg,
                    const float* __restrict__ whg, const float* __restrict__ wxg,
                    const float* __restrict__ bxg,
                    const float* __restrict__ injwg, const float* __restrict__ injbg,
                    const float* __restrict__ ow0g, const float* __restrict__ ob0g,
                    const float* __restrict__ ow1g, const float* __restrict__ ob1g,
                    const float* __restrict__ ow2g, const float* __restrict__ ob2g,
                    float* __restrict__ outg) {
  const int t  = threadIdx.x;
  const int w  = t >> 6;       // wave 0..7
  const int l  = t & 63;       // lane
  const int lr = l & 15;
  const int lg = l >> 4;       // 0..3
  const int rb = blockIdx.x * 16;  // batch-row base for this WG
  const int c1 = w * 32;       // N-slice base for 256-wide stages (2 tiles of 16)
  const int c3 = w * 16;       // N-slice base for 128-wide stages (1 tile of 16)

  __shared__ __align__(16) unsigned char lds[LDS_TOT];

  // ---------------- one-time staging into LDS ----------------
  for (int e = t; e < 16 * 64; e += 512) {
    *(float*)(lds + LDS_TS + e * 4) = ts[(size_t)(rb + (e >> 6)) * 64 + (e & 63)];
  }
  for (int e = t; e < 128 * 128; e += 512) {
    int r = e >> 7, c = e & 127;
    *(f16*)(lds + whoff(r, c * 2)) = (f16)whg[e];
  }
  {
    int r = t >> 5, d = t & 31;
    *(f16*)(lds + xoff(r, d * 2)) = (f16)Xg[(size_t)(rb + r) * 2048 + d];
  }
  if (t < 256) {
    int r = t >> 4, c = t & 15;
    *(f16*)(lds + z1off(r, (128 + c) * 2)) = (f16)Sg[(size_t)(rb + r) * 16 + c];
    *(f16*)(lds + z1off(r, (144 + c) * 2)) = (f16)0.0f;
  }

  // ---------------- per-lane constants ----------------
  float b0v[2], w0c0[2], b1v[2];
  #pragma unroll
  for (int nt = 0; nt < 2; ++nt) {
    int col = c1 + nt * 16 + lr;
    b0v[nt]  = b0g[col];
    w0c0[nt] = w0g[(size_t)col * 129];   // t-column of ode_w0
    b1v[nt]  = b1g[col];
  }
  const float b2v = b2g[c3 + lr];
  const float bxv = bxg[c3 + lr];
  const float scalev = scaleg[0];

  // ---------------- register-resident weight B-fragments (f16) ----------------
  auto ldfrag = [](const float* p) {
    f16x8 v;
    #pragma unroll
    for (int j = 0; j < 8; ++j) v[j] = (f16)p[j];
    return v;
  };

  f16x8 W0f[4][2];  // ode_w0[:,1:129] : K=128, N-slice 32
  #pragma unroll
  for (int kt = 0; kt < 4; ++kt)
    #pragma unroll
    for (int nt = 0; nt < 2; ++nt)
      W0f[kt][nt] = ldfrag(w0g + (size_t)(c1 + nt * 16 + lr) * 129 + 1 + kt * 32 + lg * 8);

  f16x8 W1f[8][2];  // ode_w1 : K=256, N-slice 32
  #pragma unroll
  for (int kt = 0; kt < 8; ++kt)
    #pragma unroll
    for (int nt = 0; nt < 2; ++nt)
      W1f[kt][nt] = ldfrag(w1g + (size_t)(c1 + nt * 16 + lr) * 256 + kt * 32 + lg * 8);

  f16x8 W2f[8];     // ode_w2 : K=256, N-slice 16
  #pragma unroll
  for (int kt = 0; kt < 8; ++kt)
    W2f[kt] = ldfrag(w2g + (size_t)(c3 + lr) * 256 + kt * 32 + lg * 8);

  f16x8 WXf = ldfrag(wxg + (size_t)(c3 + lr) * 32 + lg * 8);  // rnn_wx : K=32

  __syncthreads();  // staging complete

  // ---------------- state ----------------
  float y[4];              // per-lane h-state: elem r -> (row lg*4+r, col c3+lr)
  float tpv[4], dv[4];     // per-row t0 and substep dt

  auto writeY = [&](const float* yv) {
    #pragma unroll
    for (int r = 0; r < 4; ++r)
      *(f16*)(lds + yoff(lg * 4 + r, (c3 + lr) * 2)) = (f16)yv[r];
  };

  // ---------------- init: h0 = tanh(X0 @ wx.T + bx), then inj ----------------
  {
    f16x8 xa = *(const f16x8*)(lds + xoff(lr, lg * 16));
    f32x4 acc = {};
    acc = MFMA16(xa, WXf, acc);
    #pragma unroll
    for (int r = 0; r < 4; ++r) {
      float v = tanh_fast(acc[r] + bxv);
      *(f16*)(lds + z1off(lg * 4 + r, (c3 + lr) * 2)) = (f16)v;  // h0 -> Z1 cols 0..127
    }
  }
  __syncthreads();
  {
    // inj: K=160 (h0 | Static | zeros), B-frags streamed from global (one time)
    f16x8 af[5];
    #pragma unroll
    for (int kt = 0; kt < 5; ++kt) af[kt] = *(const f16x8*)(lds + z1off(lr, kt * 64 + lg * 16));
    f32x4 acc = {};
    int orow = c3 + lr;
    #pragma unroll
    for (int kt = 0; kt < 5; ++kt) {
      f16x8 bf;
      #pragma unroll
      for (int j = 0; j < 8; ++j) {
        int k = kt * 32 + lg * 8 + j;
        bf[j] = (k < 144) ? (f16)injwg[(size_t)orow * 144 + k] : (f16)0.0f;
      }
      acc = MFMA16(af[kt], bf, acc);
    }
    float ib = injbg[orow];
    #pragma unroll
    for (int r = 0; r < 4; ++r) y[r] = tanh_fast(acc[r] + ib);
  }
  writeY(y);
  __syncthreads();

  // ---------------- f(t,y) evaluation (3 MFMA stages) ----------------
  auto feval = [&](float sc, float* ko) {
    f16x8 af[8];
    // stage1: K=128 from Y, N=256, + t*w0[:,0] + b0, silu -> Z1  (4 acc chains)
    #pragma unroll
    for (int kt = 0; kt < 4; ++kt) af[kt] = *(const f16x8*)(lds + yoff(lr, kt * 64 + lg * 16));
    f32x4 a1[2] = {}, a1b[2] = {};
    __builtin_amdgcn_s_setprio(1);
    #pragma unroll
    for (int kt = 0; kt < 2; ++kt)
      #pragma unroll
      for (int nt = 0; nt < 2; ++nt) {
        a1[nt]  = MFMA16(af[kt],     W0f[kt][nt],     a1[nt]);
        a1b[nt] = MFMA16(af[kt + 2], W0f[kt + 2][nt], a1b[nt]);
      }
    __builtin_amdgcn_s_setprio(0);
    #pragma unroll
    for (int nt = 0; nt < 2; ++nt)
      #pragma unroll
      for (int r = 0; r < 4; ++r) {
        float tr = tpv[r] + sc * dv[r];
        float v = siluf(a1[nt][r] + a1b[nt][r] + tr * w0c0[nt] + b0v[nt]);
        *(f16*)(lds + z1off(lg * 4 + r, (c1 + nt * 16 + lr) * 2)) = (f16)v;
      }
    __syncthreads();
    // stage2: K=256 from Z1, N=256, +b1, silu -> Z2  (4 acc chains)
    #pragma unroll
    for (int kt = 0; kt < 8; ++kt) af[kt] = *(const f16x8*)(lds + z1off(lr, kt * 64 + lg * 16));
    f32x4 a2[2] = {}, a2b[2] = {};
    __builtin_amdgcn_s_setprio(1);
    #pragma unroll
    for (int kt = 0; kt < 4; ++kt)
      #pragma unroll
      for (int nt = 0; nt < 2; ++nt) {
        a2[nt]  = MFMA16(af[kt],     W1f[kt][nt],     a2[nt]);
        a2b[nt] = MFMA16(af[kt + 4], W1f[kt + 4][nt], a2b[nt]);
      }
    __builtin_amdgcn_s_setprio(0);
    #pragma unroll
    for (int nt = 0; nt < 2; ++nt)
      #pragma unroll
      for (int r = 0; r < 4; ++r) {
        float v = siluf(a2[nt][r] + a2b[nt][r] + b1v[nt]);
        *(f16*)(lds + z2off(lg * 4 + r, (c1 + nt * 16 + lr) * 2)) = (f16)v;
      }
    __syncthreads();
    // stage3: K=256 from Z2, N=128, scale*tanh(+b2) -> k (registers, 4 chains)
    #pragma unroll
    for (int kt = 0; kt < 8; ++kt) af[kt] = *(const f16x8*)(lds + z2off(lr, kt * 64 + lg * 16));
    f32x4 a3 = {}, a3b = {}, a3c = {}, a3d = {};
    __builtin_amdgcn_s_setprio(1);
    #pragma unroll
    for (int kt = 0; kt < 2; ++kt) {
      a3  = MFMA16(af[kt],     W2f[kt],     a3);
      a3b = MFMA16(af[kt + 2], W2f[kt + 2], a3b);
      a3c = MFMA16(af[kt + 4], W2f[kt + 4], a3c);
      a3d = MFMA16(af[kt + 6], W2f[kt + 6], a3d);
    }
    __builtin_amdgcn_s_setprio(0);
    #pragma unroll
    for (int r = 0; r < 4; ++r)
      ko[r] = scalev * tanh_fast(((a3[r] + a3b[r]) + (a3c[r] + a3d[r])) + b2v);
  };

  // ---------------- main time loop ----------------
  #pragma unroll 1
  for (int n = 0; n < 63; ++n) {
    #pragma unroll
    for (int r = 0; r < 4; ++r) {
      float tp = *(const float*)(lds + LDS_TS + (((lg * 4 + r) * 64) + n) * 4);
      float tn = *(const float*)(lds + LDS_TS + (((lg * 4 + r) * 64) + n + 1) * 4);
      tpv[r] = tp;
      dv[r] = (tn - tp) * 0.5f;
    }
    // stage x = X[:, n+1] for this step's RNN (consumed after many barriers)
    {
      int r = t >> 5, d = t & 31;
      *(f16*)(lds + xoff(r, d * 2)) = (f16)Xg[(size_t)(rb + r) * 2048 + (size_t)(n + 1) * 32 + d];
    }

    #pragma unroll 1
    for (int s = 0; s < 2; ++s) {
      float k1v[4], k2v[4], k3v[4], k4v[4], k5v[4], k6v[4], yt[4];
      float sf = (float)s;
      feval(sf, k1v);
      #pragma unroll
      for (int i = 0; i < 4; ++i) yt[i] = y[i] + dv[i] * (A21f * k1v[i]);
      writeY(yt); __syncthreads();
      feval(sf + C2f, k2v);
      #pragma unroll
      for (int i = 0; i < 4; ++i) yt[i] = y[i] + dv[i] * (A31f * k1v[i] + A32f * k2v[i]);
      writeY(yt); __syncthreads();
      feval(sf + C3f, k3v);
      #pragma unroll
      for (int i = 0; i < 4; ++i) yt[i] = y[i] + dv[i] * (A41f * k1v[i] + A42f * k2v[i] + A43f * k3v[i]);
      writeY(yt); __syncthreads();
      feval(sf + C4f, k4v);
      #pragma unroll
      for (int i = 0; i < 4; ++i) yt[i] = y[i] + dv[i] * (A51f * k1v[i] + A52f * k2v[i] + A53f * k3v[i] + A54f * k4v[i]);
      writeY(yt); __syncthreads();
      feval(sf + C5f, k5v);
      #pragma unroll
      for (int i = 0; i < 4; ++i) yt[i] = y[i] + dv[i] * (A61f * k1v[i] + A62f * k2v[i] + A63f * k3v[i] + A64f * k4v[i] + A65f * k5v[i]);
      writeY(yt); __syncthreads();
      feval(sf + C6f, k6v);
      #pragma unroll
      for (int i = 0; i < 4; ++i)
        y[i] += dv[i] * (B1f * k1v[i] + B2f * k2v[i] + B3f * k3v[i] + B4f * k4v[i] + B5f * k5v[i] + B6f * k6v[i]);
      writeY(y); __syncthreads();
    }

    // RNN: h = tanh(hp@wh.T + x@wx.T + bx); wh B-frags from LDS, wx from regs
    {
      f16x8 ha[4];
      #pragma unroll
      for (int kt = 0; kt < 4; ++kt) ha[kt] = *(const f16x8*)(lds + yoff(lr, kt * 64 + lg * 16));
      f16x8 xa = *(const f16x8*)(lds + xoff(lr, lg * 16));
      f32x4 acc = {}, accb = {};
      __builtin_amdgcn_s_setprio(1);
      #pragma unroll
      for (int kt = 0; kt < 2; ++kt) {
        f16x8 bf  = *(const f16x8*)(lds + whoff(c3 + lr, kt * 64 + lg * 16));
        f16x8 bf2 = *(const f16x8*)(lds + whoff(c3 + lr, (kt + 2) * 64 + lg * 16));
        acc  = MFMA16(ha[kt],     bf,  acc);
        accb = MFMA16(ha[kt + 2], bf2, accb);
      }
      acc = MFMA16(xa, WXf, acc);
      __builtin_amdgcn_s_setprio(0);
      #pragma unroll
      for (int r = 0; r < 4; ++r) y[r] = tanh_fast(acc[r] + accb[r] + bxv);
      writeY(y);
      __syncthreads();
    }
  }

  // ---------------- output head ----------------
  auto ldfrag2 = [](const float* p) {
    f16x8 v;
    #pragma unroll
    for (int j = 0; j < 8; ++j) v[j] = (f16)p[j];
    return v;
  };
  // H1: z = tanh(hN @ out_w0.T + out_b0)   K=128 -> N=256
  {
    f16x8 ha[4];
    #pragma unroll
    for (int kt = 0; kt < 4; ++kt) ha[kt] = *(const f16x8*)(lds + yoff(lr, kt * 64 + lg * 16));
    f32x4 acc[2] = {};
    #pragma unroll
    for (int kt = 0; kt < 4; ++kt)
      #pragma unroll
      for (int nt = 0; nt < 2; ++nt) {
        f16x8 bf = ldfrag2(ow0g + (size_t)(c1 + nt * 16 + lr) * 128 + kt * 32 + lg * 8);
        acc[nt] = MFMA16(ha[kt], bf, acc[nt]);
      }
    #pragma unroll
    for (int nt = 0; nt < 2; ++nt) {
      float bb = ob0g[c1 + nt * 16 + lr];
      #pragma unroll
      for (int r = 0; r < 4; ++r) {
        float v = tanh_fast(acc[nt][r] + bb);
        *(f16*)(lds + z1off(lg * 4 + r, (c1 + nt * 16 + lr) * 2)) = (f16)v;
      }
    }
  }
  __syncthreads();
  // H2: z = tanh(z @ out_w1.T + out_b1)   K=256 -> N=256
  {
    f16x8 za[8];
    #pragma unroll
    for (int kt = 0; kt < 8; ++kt) za[kt] = *(const f16x8*)(lds + z1off(lr, kt * 64 + lg * 16));
    f32x4 acc[2] = {};
    #pragma unroll
    for (int kt = 0; kt < 8; ++kt)
      #pragma unroll
      for (int nt = 0; nt < 2; ++nt) {
        f16x8 bf = ldfrag2(ow1g + (size_t)(c1 + nt * 16 + lr) * 256 + kt * 32 + lg * 8);
        acc[nt] = MFMA16(za[kt], bf, acc[nt]);
      }
    #pragma unroll
    for (int nt = 0; nt < 2; ++nt) {
      float bb = ob1g[c1 + nt * 16 + lr];
      #pragma unroll
      for (int r = 0; r < 4; ++r) {
        float v = tanh_fast(acc[nt][r] + bb);
        *(f16*)(lds + z2off(lg * 4 + r, (c1 + nt * 16 + lr) * 2)) = (f16)v;
      }
    }
  }
  __syncthreads();
  // H3: out = z @ out_w2.T + out_b2   K=256 -> N=16 (wave 0 only)
  if (w == 0) {
    f16x8 za[8];
    #pragma unroll
    for (int kt = 0; kt < 8; ++kt) za[kt] = *(const f16x8*)(lds + z2off(lr, kt * 64 + lg * 16));
    f32x4 acc = {};
    #pragma unroll
    for (int kt = 0; kt < 8; ++kt) {
      f16x8 bf = ldfrag2(ow2g + (size_t)lr * 256 + kt * 32 + lg * 8);
      acc = MFMA16(za[kt], bf, acc);
    }
    float bb = ob2g[lr];
    #pragma unroll
    for (int r = 0; r < 4; ++r)
      outg[(size_t)(rb + lg * 4 + r) * 16 + lr] = acc[r] + bb;
  }
}

extern "C" void kernel_launch(void* const* d_in, const int* in_sizes, int n_in,
                              void* d_out, int out_size, void* d_ws, size_t ws_size,
                              hipStream_t stream) {
  (void)in_sizes; (void)n_in; (void)d_ws; (void)ws_size; (void)out_size;
  ode_rnn_kernel<<<dim3(8), dim3(512), 0, stream>>>(
      (const float*)d_in[0],  (const float*)d_in[1],  (const float*)d_in[2],
      (const float*)d_in[3],  (const float*)d_in[4],  (const float*)d_in[5],
      (const float*)d_in[6],  (const float*)d_in[7],  (const float*)d_in[8],
      (const float*)d_in[9],  (const float*)d_in[10], (const float*)d_in[11],
      (const float*)d_in[12], (const float*)d_in[13], (const float*)d_in[14],
      (const float*)d_in[15], (const float*)d_in[16], (const float*)d_in[17],
      (const float*)d_in[18], (const float*)d_in[19], (const float*)d_in[20],
      (float*)d_out);
}

// Round 4
// 1224.612 us; speedup vs baseline: 1.0441x; 1.0441x over previous
//
#include <hip/hip_runtime.h>

typedef _Float16 f16;
typedef _Float16 f16x8 __attribute__((ext_vector_type(8)));
typedef float f32x4 __attribute__((ext_vector_type(4)));

#define MFMA16(a, b, c) __builtin_amdgcn_mfma_f32_16x16x32_f16((a), (b), (c), 0, 0, 0)

// ---- Tsit5 coefficients (fp32) ----
#define A21f 0.161f
#define A31f (-0.008480655492356989f)
#define A32f 0.335480655492357f
#define A41f 2.8971530571054935f
#define A42f (-6.359448489975075f)
#define A43f 4.3622954328695815f
#define A51f 5.325864828439257f
#define A52f (-11.748883564062828f)
#define A53f 7.4955393428898365f
#define A54f (-0.09249506636175525f)
#define A61f 5.86145544294642f
#define A62f (-12.92096931784711f)
#define A63f 8.159367898576159f
#define A64f (-0.071584973281401f)
#define A65f (-0.028269050394068383f)
#define B1f 0.09646076681806523f
#define B2f 0.01f
#define B3f 0.4798896504144996f
#define B4f 1.379008574103742f
#define B5f (-3.290069515436081f)
#define B6f 2.324710524099774f
#define C2f 0.161f
#define C3f 0.327f
#define C4f 0.9f
#define C5f 0.9800255409045097f
#define C6f 1.0f

// ---- LDS layout: FRAGMENT-MAJOR activation tiles ----
// addr(row, k) = base + ((k>>3)*16 + row)*16 + (k&7)*2
// => A-frag read (kt) for lane l is ds_read_b128 at base + kt*1024 + l*16
//    (1024 contiguous bytes per wave instruction: provably conflict-free)
// Y  : 16 rows x 128 k  (4 KB)
// Z1 : 16 rows x 256 k  (8 KB)   [cols 128..159 = Static|zeros for inj]
// Z2 : 16 rows x 256 k  (8 KB)
// X  : 16 rows x  32 k  (1 KB)
// TS : 16 x 64 f32 linear (4 KB)
// WH : 128 out x 128 k fragment-major: addr(c,k)=((k>>3)*128+c)*16+(k&7)*2 (32 KB)
#define LDS_Y   0
#define LDS_Z1  4096
#define LDS_Z2  12288
#define LDS_X   20480
#define LDS_TS  21504
#define LDS_WH  25600
#define LDS_TOT 58368

// branch-free fast activations (v_exp + v_rcp)
__device__ __forceinline__ float tanh_fast(float x) {
  return 2.0f * __builtin_amdgcn_rcpf(1.0f + __expf(-2.0f * x)) - 1.0f;
}
__device__ __forceinline__ float siluf(float x) {
  return x * __builtin_amdgcn_rcpf(1.0f + __expf(-x));
}

__global__ __launch_bounds__(512, 2)
void ode_rnn_kernel(const float* __restrict__ ts, const float* __restrict__ Xg,
                    const float* __restrict__ Sg,
                    const float* __restrict__ w0g, const float* __restrict__ b0g,
                    const float* __restrict__ w1g, const float* __restrict__ b1g,
                    const float* __restrict__ w2g, const float* __restrict__ b2g,
                    const float* __restrict__ scaleg,
                    const float* __restrict__ whg, const float* __restrict__ wxg,
                    const float* __restrict__ bxg,
                    const float* __restrict__ injwg, const float* __restrict__ injbg,
                    const float* __restrict__ ow0g, const float* __restrict__ ob0g,
                    const float* __restrict__ ow1g, const float* __restrict__ ob1g,
                    const float* __restrict__ ow2g, const float* __restrict__ ob2g,
                    float* __restrict__ outg) {
  const int t  = threadIdx.x;
  const int w  = t >> 6;       // wave 0..7
  const int l  = t & 63;       // lane
  const int lr = l & 15;
  const int lg = l >> 4;       // 0..3
  const int rb = blockIdx.x * 16;  // batch-row base for this WG
  const int c1 = w * 32;       // N-slice base for 256-wide stages (2 tiles of 16)
  const int c3 = w * 16;       // N-slice base for 128-wide stages (1 tile of 16)

  __shared__ __align__(16) unsigned char lds[LDS_TOT];

  // per-lane precomputed addresses
  const int ard  = l * 16;                                        // A-frag read base (all act tiles)
  const int whrd = LDS_WH + lg * 2048 + w * 256 + lr * 16;        // WH B-frag base (+kt*8192)
  const int zw   = w * 1024 + (lr >> 3) * 256 + lg * 64 + (lr & 7) * 2; // Z write base (+nt*512+r*16)
  const int yw   = w * 512  + (lr >> 3) * 256 + lg * 64 + (lr & 7) * 2; // Y write base (+r*16)

  // ---------------- one-time staging into LDS ----------------
  for (int e = t; e < 16 * 64; e += 512) {
    *(float*)(lds + LDS_TS + e * 4) = ts[(size_t)(rb + (e >> 6)) * 64 + (e & 63)];
  }
  for (int e = t; e < 128 * 128; e += 512) {
    int c = e >> 7, kk = e & 127;
    *(f16*)(lds + LDS_WH + ((kk >> 3) * 128 + c) * 16 + (kk & 7) * 2) = (f16)whg[e];
  }
  {
    int r = t >> 5, d = t & 31;
    *(f16*)(lds + LDS_X + (d >> 3) * 256 + r * 16 + (d & 7) * 2) =
        (f16)Xg[(size_t)(rb + r) * 2048 + d];
  }
  if (t < 256) {
    int r = t >> 4, c = t & 15;
    // Static -> Z1 k=128..143 ; zeros -> k=144..159
    *(f16*)(lds + LDS_Z1 + 4096 + (c >> 3) * 256 + r * 16 + (c & 7) * 2) =
        (f16)Sg[(size_t)(rb + r) * 16 + c];
    *(f16*)(lds + LDS_Z1 + 4608 + (c >> 3) * 256 + r * 16 + (c & 7) * 2) = (f16)0.0f;
  }

  // ---------------- per-lane constants ----------------
  float b0v[2], w0c0[2], b1v[2];
  #pragma unroll
  for (int nt = 0; nt < 2; ++nt) {
    int col = c1 + nt * 16 + lr;
    b0v[nt]  = b0g[col];
    w0c0[nt] = w0g[(size_t)col * 129];   // t-column of ode_w0
    b1v[nt]  = b1g[col];
  }
  const float b2v = b2g[c3 + lr];
  const float bxv = bxg[c3 + lr];
  const float scalev = scaleg[0];

  // ---------------- register-resident weight B-fragments (f16) ----------------
  auto ldfrag = [](const float* p) {
    f16x8 v;
    #pragma unroll
    for (int j = 0; j < 8; ++j) v[j] = (f16)p[j];
    return v;
  };

  f16x8 W0f[4][2];  // ode_w0[:,1:129] : K=128, N-slice 32
  #pragma unroll
  for (int kt = 0; kt < 4; ++kt)
    #pragma unroll
    for (int nt = 0; nt < 2; ++nt)
      W0f[kt][nt] = ldfrag(w0g + (size_t)(c1 + nt * 16 + lr) * 129 + 1 + kt * 32 + lg * 8);

  f16x8 W1f[8][2];  // ode_w1 : K=256, N-slice 32
  #pragma unroll
  for (int kt = 0; kt < 8; ++kt)
    #pragma unroll
    for (int nt = 0; nt < 2; ++nt)
      W1f[kt][nt] = ldfrag(w1g + (size_t)(c1 + nt * 16 + lr) * 256 + kt * 32 + lg * 8);

  f16x8 W2f[8];     // ode_w2 : K=256, N-slice 16
  #pragma unroll
  for (int kt = 0; kt < 8; ++kt)
    W2f[kt] = ldfrag(w2g + (size_t)(c3 + lr) * 256 + kt * 32 + lg * 8);

  f16x8 WXf = ldfrag(wxg + (size_t)(c3 + lr) * 32 + lg * 8);  // rnn_wx : K=32

  __syncthreads();  // staging complete

  // ---------------- state ----------------
  float y[4];              // per-lane h-state: elem r -> (row lg*4+r, col c3+lr)
  float tpv[4], dv[4];     // per-row t0 and substep dt

  auto writeY = [&](const float* yv) {
    #pragma unroll
    for (int r = 0; r < 4; ++r)
      *(f16*)(lds + LDS_Y + yw + r * 16) = (f16)yv[r];
  };

  // ---------------- init: h0 = tanh(X0 @ wx.T + bx), then inj ----------------
  {
    f16x8 xa = *(const f16x8*)(lds + LDS_X + ard);
    f32x4 acc = {};
    acc = MFMA16(xa, WXf, acc);
    #pragma unroll
    for (int r = 0; r < 4; ++r) {
      float v = tanh_fast(acc[r] + bxv);
      *(f16*)(lds + LDS_Z1 + yw + r * 16) = (f16)v;  // h0 -> Z1 k=0..127 (same frag map as Y)
    }
  }
  __syncthreads();
  {
    // inj: K=160 (h0 | Static | zeros), B-frags streamed from global (one time)
    f16x8 af[5];
    #pragma unroll
    for (int kt = 0; kt < 5; ++kt) af[kt] = *(const f16x8*)(lds + LDS_Z1 + ard + kt * 1024);
    f32x4 acc = {};
    int orow = c3 + lr;
    #pragma unroll
    for (int kt = 0; kt < 5; ++kt) {
      f16x8 bf;
      #pragma unroll
      for (int j = 0; j < 8; ++j) {
        int k = kt * 32 + lg * 8 + j;
        bf[j] = (k < 144) ? (f16)injwg[(size_t)orow * 144 + k] : (f16)0.0f;
      }
      acc = MFMA16(af[kt], bf, acc);
    }
    float ib = injbg[orow];
    #pragma unroll
    for (int r = 0; r < 4; ++r) y[r] = tanh_fast(acc[r] + ib);
  }
  writeY(y);
  __syncthreads();

  // ---------------- f(t,y) evaluation (3 MFMA stages) ----------------
  auto feval = [&](float sc, float* ko) {
    f16x8 af[8];
    // stage1: K=128 from Y, N=256, + t*w0[:,0] + b0, silu -> Z1  (4 acc chains)
    #pragma unroll
    for (int kt = 0; kt < 4; ++kt) af[kt] = *(const f16x8*)(lds + LDS_Y + ard + kt * 1024);
    f32x4 a1[2] = {}, a1b[2] = {};
    __builtin_amdgcn_s_setprio(1);
    #pragma unroll
    for (int kt = 0; kt < 2; ++kt)
      #pragma unroll
      for (int nt = 0; nt < 2; ++nt) {
        a1[nt]  = MFMA16(af[kt],     W0f[kt][nt],     a1[nt]);
        a1b[nt] = MFMA16(af[kt + 2], W0f[kt + 2][nt], a1b[nt]);
      }
    __builtin_amdgcn_s_setprio(0);
    #pragma unroll
    for (int r = 0; r < 4; ++r) {
      float tr = tpv[r] + sc * dv[r];
      #pragma unroll
      for (int nt = 0; nt < 2; ++nt) {
        float v = siluf(a1[nt][r] + a1b[nt][r] + tr * w0c0[nt] + b0v[nt]);
        *(f16*)(lds + LDS_Z1 + zw + nt * 512 + r * 16) = (f16)v;
      }
    }
    __syncthreads();
    // stage2: K=256 from Z1, N=256, +b1, silu -> Z2  (4 acc chains)
    #pragma unroll
    for (int kt = 0; kt < 8; ++kt) af[kt] = *(const f16x8*)(lds + LDS_Z1 + ard + kt * 1024);
    f32x4 a2[2] = {}, a2b[2] = {};
    __builtin_amdgcn_s_setprio(1);
    #pragma unroll
    for (int kt = 0; kt < 4; ++kt)
      #pragma unroll
      for (int nt = 0; nt < 2; ++nt) {
        a2[nt]  = MFMA16(af[kt],     W1f[kt][nt],     a2[nt]);
        a2b[nt] = MFMA16(af[kt + 4], W1f[kt + 4][nt], a2b[nt]);
      }
    __builtin_amdgcn_s_setprio(0);
    #pragma unroll
    for (int nt = 0; nt < 2; ++nt)
      #pragma unroll
      for (int r = 0; r < 4; ++r) {
        float v = siluf(a2[nt][r] + a2b[nt][r] + b1v[nt]);
        *(f16*)(lds + LDS_Z2 + zw + nt * 512 + r * 16) = (f16)v;
      }
    __syncthreads();
    // stage3: K=256 from Z2, N=128, scale*tanh(+b2) -> k (registers, 4 chains)
    #pragma unroll
    for (int kt = 0; kt < 8; ++kt) af[kt] = *(const f16x8*)(lds + LDS_Z2 + ard + kt * 1024);
    f32x4 a3 = {}, a3b = {}, a3c = {}, a3d = {};
    __builtin_amdgcn_s_setprio(1);
    #pragma unroll
    for (int kt = 0; kt < 2; ++kt) {
      a3  = MFMA16(af[kt],     W2f[kt],     a3);
      a3b = MFMA16(af[kt + 2], W2f[kt + 2], a3b);
      a3c = MFMA16(af[kt + 4], W2f[kt + 4], a3c);
      a3d = MFMA16(af[kt + 6], W2f[kt + 6], a3d);
    }
    __builtin_amdgcn_s_setprio(0);
    #pragma unroll
    for (int r = 0; r < 4; ++r)
      ko[r] = scalev * tanh_fast(((a3[r] + a3b[r]) + (a3c[r] + a3d[r])) + b2v);
  };

  // ---------------- main time loop ----------------
  #pragma unroll 1
  for (int n = 0; n < 63; ++n) {
    #pragma unroll
    for (int r = 0; r < 4; ++r) {
      float tp = *(const float*)(lds + LDS_TS + (((lg * 4 + r) * 64) + n) * 4);
      float tn = *(const float*)(lds + LDS_TS + (((lg * 4 + r) * 64) + n + 1) * 4);
      tpv[r] = tp;
      dv[r] = (tn - tp) * 0.5f;
    }
    // stage x = X[:, n+1] for this step's RNN (consumed after many barriers)
    {
      int r = t >> 5, d = t & 31;
      *(f16*)(lds + LDS_X + (d >> 3) * 256 + r * 16 + (d & 7) * 2) =
          (f16)Xg[(size_t)(rb + r) * 2048 + (size_t)(n + 1) * 32 + d];
    }

    #pragma unroll 1
    for (int s = 0; s < 2; ++s) {
      float k1v[4], k2v[4], k3v[4], k4v[4], k5v[4], k6v[4], yt[4];
      float sf = (float)s;
      feval(sf, k1v);
      #pragma unroll
      for (int i = 0; i < 4; ++i) yt[i] = y[i] + dv[i] * (A21f * k1v[i]);
      writeY(yt); __syncthreads();
      feval(sf + C2f, k2v);
      #pragma unroll
      for (int i = 0; i < 4; ++i) yt[i] = y[i] + dv[i] * (A31f * k1v[i] + A32f * k2v[i]);
      writeY(yt); __syncthreads();
      feval(sf + C3f, k3v);
      #pragma unroll
      for (int i = 0; i < 4; ++i) yt[i] = y[i] + dv[i] * (A41f * k1v[i] + A42f * k2v[i] + A43f * k3v[i]);
      writeY(yt); __syncthreads();
      feval(sf + C4f, k4v);
      #pragma unroll
      for (int i = 0; i < 4; ++i) yt[i] = y[i] + dv[i] * (A51f * k1v[i] + A52f * k2v[i] + A53f * k3v[i] + A54f * k4v[i]);
      writeY(yt); __syncthreads();
      feval(sf + C5f, k5v);
      #pragma unroll
      for (int i = 0; i < 4; ++i) yt[i] = y[i] + dv[i] * (A61f * k1v[i] + A62f * k2v[i] + A63f * k3v[i] + A64f * k4v[i] + A65f * k5v[i]);
      writeY(yt); __syncthreads();
      feval(sf + C6f, k6v);
      #pragma unroll
      for (int i = 0; i < 4; ++i)
        y[i] += dv[i] * (B1f * k1v[i] + B2f * k2v[i] + B3f * k3v[i] + B4f * k4v[i] + B5f * k5v[i] + B6f * k6v[i]);
      writeY(y); __syncthreads();
    }

    // RNN: h = tanh(hp@wh.T + x@wx.T + bx); wh B-frags from LDS, wx from regs
    {
      f16x8 ha[4];
      #pragma unroll
      for (int kt = 0; kt < 4; ++kt) ha[kt] = *(const f16x8*)(lds + LDS_Y + ard + kt * 1024);
      f16x8 xa = *(const f16x8*)(lds + LDS_X + ard);
      f32x4 acc = {}, accb = {};
      __builtin_amdgcn_s_setprio(1);
      #pragma unroll
      for (int kt = 0; kt < 2; ++kt) {
        f16x8 bf  = *(const f16x8*)(lds + whrd + kt * 8192);
        f16x8 bf2 = *(const f16x8*)(lds + whrd + (kt + 2) * 8192);
        acc  = MFMA16(ha[kt],     bf,  acc);
        accb = MFMA16(ha[kt + 2], bf2, accb);
      }
      acc = MFMA16(xa, WXf, acc);
      __builtin_amdgcn_s_setprio(0);
      #pragma unroll
      for (int r = 0; r < 4; ++r) y[r] = tanh_fast(acc[r] + accb[r] + bxv);
      writeY(y);
      __syncthreads();
    }
  }

  // ---------------- output head ----------------
  auto ldfrag2 = [](const float* p) {
    f16x8 v;
    #pragma unroll
    for (int j = 0; j < 8; ++j) v[j] = (f16)p[j];
    return v;
  };
  // H1: z = tanh(hN @ out_w0.T + out_b0)   K=128 -> N=256
  {
    f16x8 ha[4];
    #pragma unroll
    for (int kt = 0; kt < 4; ++kt) ha[kt] = *(const f16x8*)(lds + LDS_Y + ard + kt * 1024);
    f32x4 acc[2] = {};
    #pragma unroll
    for (int kt = 0; kt < 4; ++kt)
      #pragma unroll
      for (int nt = 0; nt < 2; ++nt) {
        f16x8 bf = ldfrag2(ow0g + (size_t)(c1 + nt * 16 + lr) * 128 + kt * 32 + lg * 8);
        acc[nt] = MFMA16(ha[kt], bf, acc[nt]);
      }
    #pragma unroll
    for (int nt = 0; nt < 2; ++nt) {
      float bb = ob0g[c1 + nt * 16 + lr];
      #pragma unroll
      for (int r = 0; r < 4; ++r) {
        float v = tanh_fast(acc[nt][r] + bb);
        *(f16*)(lds + LDS_Z1 + zw + nt * 512 + r * 16) = (f16)v;
      }
    }
  }
  __syncthreads();
  // H2: z = tanh(z @ out_w1.T + out_b1)   K=256 -> N=256
  {
    f16x8 za[8];
    #pragma unroll
    for (int kt = 0; kt < 8; ++kt) za[kt] = *(const f16x8*)(lds + LDS_Z1 + ard + kt * 1024);
    f32x4 acc[2] = {};
    #pragma unroll
    for (int kt = 0; kt < 8; ++kt)
      #pragma unroll
      for (int nt = 0; nt < 2; ++nt) {
        f16x8 bf = ldfrag2(ow1g + (size_t)(c1 + nt * 16 + lr) * 256 + kt * 32 + lg * 8);
        acc[nt] = MFMA16(za[kt], bf, acc[nt]);
      }
    #pragma unroll
    for (int nt = 0; nt < 2; ++nt) {
      float bb = ob1g[c1 + nt * 16 + lr];
      #pragma unroll
      for (int r = 0; r < 4; ++r) {
        float v = tanh_fast(acc[nt][r] + bb);
        *(f16*)(lds + LDS_Z2 + zw + nt * 512 + r * 16) = (f16)v;
      }
    }
  }
  __syncthreads();
  // H3: out = z @ out_w2.T + out_b2   K=256 -> N=16 (wave 0 only)
  if (w == 0) {
    f16x8 za[8];
    #pragma unroll
    for (int kt = 0; kt < 8; ++kt) za[kt] = *(const f16x8*)(lds + LDS_Z2 + ard + kt * 1024);
    f32x4 acc = {};
    #pragma unroll
    for (int kt = 0; kt < 8; ++kt) {
      f16x8 bf = ldfrag2(ow2g + (size_t)lr * 256 + kt * 32 + lg * 8);
      acc = MFMA16(za[kt], bf, acc);
    }
    float bb = ob2g[lr];
    #pragma unroll
    for (int r = 0; r < 4; ++r)
      outg[(size_t)(rb + lg * 4 + r) * 16 + lr] = acc[r] + bb;
  }
}

extern "C" void kernel_launch(void* const* d_in, const int* in_sizes, int n_in,
                              void* d_out, int out_size, void* d_ws, size_t ws_size,
                              hipStream_t stream) {
  (void)in_sizes; (void)n_in; (void)d_ws; (void)ws_size; (void)out_size;
  ode_rnn_kernel<<<dim3(8), dim3(512), 0, stream>>>(
      (const float*)d_in[0],  (const float*)d_in[1],  (const float*)d_in[2],
      (const float*)d_in[3],  (const float*)d_in[4],  (const float*)d_in[5],
      (const float*)d_in[6],  (const float*)d_in[7],  (const float*)d_in[8],
      (const float*)d_in[9],  (const float*)d_in[10], (const float*)d_in[11],
      (const float*)d_in[12], (const float*)d_in[13], (const float*)d_in[14],
      (const float*)d_in[15], (const float*)d_in[16], (const float*)d_in[17],
      (const float*)d_in[18], (const float*)d_in[19], (const float*)d_in[20],
      (float*)d_out);
}

// Round 5
// 1162.703 us; speedup vs baseline: 1.0997x; 1.0532x over previous
//
#include <hip/hip_runtime.h>

typedef _Float16 f16;
typedef _Float16 f16x4 __attribute__((ext_vector_type(4)));
typedef _Float16 f16x8 __attribute__((ext_vector_type(8)));
typedef float f32x4 __attribute__((ext_vector_type(4)));

#define MFMA16(a, b, c) __builtin_amdgcn_mfma_f32_16x16x32_f16((a), (b), (c), 0, 0, 0)

// ---- Tsit5 coefficients (fp32) ----
#define A21f 0.161f
#define A31f (-0.008480655492356989f)
#define A32f 0.335480655492357f
#define A41f 2.8971530571054935f
#define A42f (-6.359448489975075f)
#define A43f 4.3622954328695815f
#define A51f 5.325864828439257f
#define A52f (-11.748883564062828f)
#define A53f 7.4955393428898365f
#define A54f (-0.09249506636175525f)
#define A61f 5.86145544294642f
#define A62f (-12.92096931784711f)
#define A63f 8.159367898576159f
#define A64f (-0.071584973281401f)
#define A65f (-0.028269050394068383f)
#define B1f 0.09646076681806523f
#define B2f 0.01f
#define B3f 0.4798896504144996f
#define B4f 1.379008574103742f
#define B5f (-3.290069515436081f)
#define B6f 2.324710524099774f
#define C2f 0.161f
#define C3f 0.327f
#define C4f 0.9f
#define C5f 0.9800255409045097f
#define C6f 1.0f

// ---- LDS layout: FRAGMENT-MAJOR activation tiles ----
// addr(row, k) = base + ((k>>3)*16 + row)*16 + (k&7)*2
//   reads : lane l does ds_read_b128 at base + kt*1024 + l*16  (conflict-free)
//   writes: swapped-operand MFMA gives lane 4 consecutive k for batch row lr
//           -> one ds_write_b64 at base + group*256 + lr*16 + (lg&1)*8 (even spread)
// Y  : 16 rows x 128 k (4 KB) | Z1/Z2: 16 x 256 k (8 KB each; Z1 k>=128 = Static|0)
// X  : 16 x 32 k (1 KB) | TS : 16x64 f32 linear (4 KB)
// WH : 128 out x 128 k fragment-major: addr(c,k)=((k>>3)*128+c)*16+(k&7)*2 (32 KB)
#define LDS_Y   0
#define LDS_Z1  4096
#define LDS_Z2  12288
#define LDS_X   20480
#define LDS_TS  21504
#define LDS_WH  25600
#define LDS_TOT 58368

// branch-free fast activations (v_exp + v_rcp)
__device__ __forceinline__ float tanh_fast(float x) {
  return 2.0f * __builtin_amdgcn_rcpf(1.0f + __expf(-2.0f * x)) - 1.0f;
}
__device__ __forceinline__ float siluf(float x) {
  return x * __builtin_amdgcn_rcpf(1.0f + __expf(-x));
}

__global__ __launch_bounds__(512, 2)
void ode_rnn_kernel(const float* __restrict__ ts, const float* __restrict__ Xg,
                    const float* __restrict__ Sg,
                    const float* __restrict__ w0g, const float* __restrict__ b0g,
                    const float* __restrict__ w1g, const float* __restrict__ b1g,
                    const float* __restrict__ w2g, const float* __restrict__ b2g,
                    const float* __restrict__ scaleg,
                    const float* __restrict__ whg, const float* __restrict__ wxg,
                    const float* __restrict__ bxg,
                    const float* __restrict__ injwg, const float* __restrict__ injbg,
                    const float* __restrict__ ow0g, const float* __restrict__ ob0g,
                    const float* __restrict__ ow1g, const float* __restrict__ ob1g,
                    const float* __restrict__ ow2g, const float* __restrict__ ob2g,
                    float* __restrict__ outg) {
  const int t  = threadIdx.x;
  const int w  = t >> 6;       // wave 0..7
  const int l  = t & 63;       // lane
  const int lr = l & 15;       // batch row owned by this lane (swapped layout)
  const int lg = l >> 4;       // 0..3
  const int rb = blockIdx.x * 16;  // batch-row base for this WG
  const int c1 = w * 32;       // out-channel base, 256-wide stages (2 tiles of 16)
  const int c3 = w * 16;       // out-channel base, 128-wide stages (1 tile of 16)

  __shared__ __align__(16) unsigned char lds[LDS_TOT];

  // per-lane precomputed addresses
  const int ard = l * 16;                                  // frag read base (+kt*1024)
  const int whrd = LDS_WH + lg * 2048 + w * 256 + lr * 16; // WH A-frag base (+kt*8192)
  const int awb = (lg >> 1) * 256 + lr * 16 + (lg & 1) * 8; // b64 write base

  // ---------------- one-time staging into LDS ----------------
  for (int e = t; e < 16 * 64; e += 512) {
    *(float*)(lds + LDS_TS + e * 4) = ts[(size_t)(rb + (e >> 6)) * 64 + (e & 63)];
  }
  for (int e = t; e < 128 * 128; e += 512) {
    int c = e >> 7, kk = e & 127;
    *(f16*)(lds + LDS_WH + ((kk >> 3) * 128 + c) * 16 + (kk & 7) * 2) = (f16)whg[e];
  }
  {
    int r = t >> 5, d = t & 31;
    *(f16*)(lds + LDS_X + (d >> 3) * 256 + r * 16 + (d & 7) * 2) =
        (f16)Xg[(size_t)(rb + r) * 2048 + d];
  }
  if (t < 256) {
    int r = t >> 4, c = t & 15;
    // Static -> Z1 k=128..143 ; zeros -> k=144..159
    *(f16*)(lds + LDS_Z1 + 4096 + (c >> 3) * 256 + r * 16 + (c & 7) * 2) =
        (f16)Sg[(size_t)(rb + r) * 16 + c];
    *(f16*)(lds + LDS_Z1 + 4608 + (c >> 3) * 256 + r * 16 + (c & 7) * 2) = (f16)0.0f;
  }

  // ---------------- per-channel constants (lane holds chans base+lg*4+r) ----------------
  f32x4 b0q[2], b1q[2];
  float w0c0[2][4];
  #pragma unroll
  for (int nt = 0; nt < 2; ++nt) {
    b0q[nt] = *(const f32x4*)(b0g + c1 + nt * 16 + lg * 4);
    b1q[nt] = *(const f32x4*)(b1g + c1 + nt * 16 + lg * 4);
    #pragma unroll
    for (int r = 0; r < 4; ++r)
      w0c0[nt][r] = w0g[(size_t)(c1 + nt * 16 + lg * 4 + r) * 129];  // t-column
  }
  const f32x4 b2q = *(const f32x4*)(b2g + c3 + lg * 4);
  const f32x4 bxq = *(const f32x4*)(bxg + c3 + lg * 4);
  const float scalev = scaleg[0];

  // ---------------- register-resident weight fragments (f16, A-operand) ----------------
  // lane holds out_ch = base + lr, k = kt*32 + lg*8 + j  (valid A-frag layout)
  auto ldfrag = [](const float* p) {
    f16x8 v;
    #pragma unroll
    for (int j = 0; j < 8; ++j) v[j] = (f16)p[j];
    return v;
  };

  f16x8 W0f[4][2];  // ode_w0[:,1:129] : K=128, chan-slice 32
  #pragma unroll
  for (int kt = 0; kt < 4; ++kt)
    #pragma unroll
    for (int nt = 0; nt < 2; ++nt)
      W0f[kt][nt] = ldfrag(w0g + (size_t)(c1 + nt * 16 + lr) * 129 + 1 + kt * 32 + lg * 8);

  f16x8 W1f[8][2];  // ode_w1 : K=256, chan-slice 32
  #pragma unroll
  for (int kt = 0; kt < 8; ++kt)
    #pragma unroll
    for (int nt = 0; nt < 2; ++nt)
      W1f[kt][nt] = ldfrag(w1g + (size_t)(c1 + nt * 16 + lr) * 256 + kt * 32 + lg * 8);

  f16x8 W2f[8];     // ode_w2 : K=256, chan-slice 16
  #pragma unroll
  for (int kt = 0; kt < 8; ++kt)
    W2f[kt] = ldfrag(w2g + (size_t)(c3 + lr) * 256 + kt * 32 + lg * 8);

  f16x8 WXf = ldfrag(wxg + (size_t)(c3 + lr) * 32 + lg * 8);  // rnn_wx : K=32

  __syncthreads();  // staging complete

  // ---------------- state ----------------
  // y[r] = h[batch = lr][chan = c3 + lg*4 + r], fp32
  float y[4];
  float tpv, dvv;   // per-lane (batch=lr) t0 and substep dt

  auto writeY = [&](const float* yv) {
    f16x4 p;
    #pragma unroll
    for (int r = 0; r < 4; ++r) p[r] = (f16)yv[r];
    *(f16x4*)(lds + LDS_Y + w * 512 + awb) = p;
  };

  // ---------------- init: h0 = tanh(X0 @ wx.T + bx), then inj ----------------
  {
    f16x8 xa = *(const f16x8*)(lds + LDS_X + ard);
    f32x4 acc = {};
    acc = MFMA16(WXf, xa, acc);          // D[chan][batch]
    f16x4 p;
    #pragma unroll
    for (int r = 0; r < 4; ++r) p[r] = (f16)tanh_fast(acc[r] + bxq[r]);
    *(f16x4*)(lds + LDS_Z1 + w * 512 + awb) = p;   // h0 -> Z1 k=0..127
  }
  __syncthreads();
  {
    // inj: K=160 (h0 | Static | zeros), A-frags streamed from global (one time)
    f16x8 af[5];
    #pragma unroll
    for (int kt = 0; kt < 5; ++kt) af[kt] = *(const f16x8*)(lds + LDS_Z1 + ard + kt * 1024);
    f32x4 acc = {};
    #pragma unroll
    for (int kt = 0; kt < 5; ++kt) {
      f16x8 bf;
      #pragma unroll
      for (int j = 0; j < 8; ++j) {
        int k = kt * 32 + lg * 8 + j;
        bf[j] = (k < 144) ? (f16)injwg[(size_t)(c3 + lr) * 144 + k] : (f16)0.0f;
      }
      acc = MFMA16(bf, af[kt], acc);     // W as A, activations as B
    }
    const f32x4 ibq = *(const f32x4*)(injbg + c3 + lg * 4);
    #pragma unroll
    for (int r = 0; r < 4; ++r) y[r] = tanh_fast(acc[r] + ibq[r]);
  }
  writeY(y);
  __syncthreads();

  // ---------------- f(t,y) evaluation (3 MFMA stages, swapped operands) ----------------
  auto feval = [&](float sc, float* ko) {
    f16x8 af[8];
    // stage1: K=128 from Y, 256 chans, + t*w0[:,0] + b0, silu -> Z1
    #pragma unroll
    for (int kt = 0; kt < 4; ++kt) af[kt] = *(const f16x8*)(lds + LDS_Y + ard + kt * 1024);
    f32x4 a1[2] = {}, a1b[2] = {};
    __builtin_amdgcn_s_setprio(1);
    #pragma unroll
    for (int kt = 0; kt < 2; ++kt)
      #pragma unroll
      for (int nt = 0; nt < 2; ++nt) {
        a1[nt]  = MFMA16(W0f[kt][nt],     af[kt],     a1[nt]);
        a1b[nt] = MFMA16(W0f[kt + 2][nt], af[kt + 2], a1b[nt]);
      }
    __builtin_amdgcn_s_setprio(0);
    const float tr = tpv + sc * dvv;
    #pragma unroll
    for (int nt = 0; nt < 2; ++nt) {
      f16x4 p;
      #pragma unroll
      for (int r = 0; r < 4; ++r)
        p[r] = (f16)siluf(a1[nt][r] + a1b[nt][r] + tr * w0c0[nt][r] + b0q[nt][r]);
      *(f16x4*)(lds + LDS_Z1 + w * 1024 + nt * 512 + awb) = p;
    }
    __syncthreads();
    // stage2: K=256 from Z1, 256 chans, +b1, silu -> Z2
    #pragma unroll
    for (int kt = 0; kt < 8; ++kt) af[kt] = *(const f16x8*)(lds + LDS_Z1 + ard + kt * 1024);
    f32x4 a2[2] = {}, a2b[2] = {};
    __builtin_amdgcn_s_setprio(1);
    #pragma unroll
    for (int kt = 0; kt < 4; ++kt)
      #pragma unroll
      for (int nt = 0; nt < 2; ++nt) {
        a2[nt]  = MFMA16(W1f[kt][nt],     af[kt],     a2[nt]);
        a2b[nt] = MFMA16(W1f[kt + 4][nt], af[kt + 4], a2b[nt]);
      }
    __builtin_amdgcn_s_setprio(0);
    #pragma unroll
    for (int nt = 0; nt < 2; ++nt) {
      f16x4 p;
      #pragma unroll
      for (int r = 0; r < 4; ++r)
        p[r] = (f16)siluf(a2[nt][r] + a2b[nt][r] + b1q[nt][r]);
      *(f16x4*)(lds + LDS_Z2 + w * 1024 + nt * 512 + awb) = p;
    }
    __syncthreads();
    // stage3: K=256 from Z2, 128 chans, scale*tanh(+b2) -> k (registers, 4 chains)
    #pragma unroll
    for (int kt = 0; kt < 8; ++kt) af[kt] = *(const f16x8*)(lds + LDS_Z2 + ard + kt * 1024);
    f32x4 a3 = {}, a3b = {}, a3c = {}, a3d = {};
    __builtin_amdgcn_s_setprio(1);
    #pragma unroll
    for (int kt = 0; kt < 2; ++kt) {
      a3  = MFMA16(W2f[kt],     af[kt],     a3);
      a3b = MFMA16(W2f[kt + 2], af[kt + 2], a3b);
      a3c = MFMA16(W2f[kt + 4], af[kt + 4], a3c);
      a3d = MFMA16(W2f[kt + 6], af[kt + 6], a3d);
    }
    __builtin_amdgcn_s_setprio(0);
    #pragma unroll
    for (int r = 0; r < 4; ++r)
      ko[r] = scalev * tanh_fast(((a3[r] + a3b[r]) + (a3c[r] + a3d[r])) + b2q[r]);
  };

  // ---------------- main time loop ----------------
  #pragma unroll 1
  for (int n = 0; n < 63; ++n) {
    {
      float tp = *(const float*)(lds + LDS_TS + (lr * 64 + n) * 4);
      float tn = *(const float*)(lds + LDS_TS + (lr * 64 + n + 1) * 4);
      tpv = tp;
      dvv = (tn - tp) * 0.5f;
    }
    // stage x = X[:, n+1] for this step's RNN (consumed after many barriers)
    {
      int r = t >> 5, d = t & 31;
      *(f16*)(lds + LDS_X + (d >> 3) * 256 + r * 16 + (d & 7) * 2) =
          (f16)Xg[(size_t)(rb + r) * 2048 + (size_t)(n + 1) * 32 + d];
    }

    #pragma unroll 1
    for (int s = 0; s < 2; ++s) {
      float k1v[4], k2v[4], k3v[4], k4v[4], k5v[4], k6v[4], yt[4];
      float sf = (float)s;
      feval(sf, k1v);
      #pragma unroll
      for (int i = 0; i < 4; ++i) yt[i] = y[i] + dvv * (A21f * k1v[i]);
      writeY(yt); __syncthreads();
      feval(sf + C2f, k2v);
      #pragma unroll
      for (int i = 0; i < 4; ++i) yt[i] = y[i] + dvv * (A31f * k1v[i] + A32f * k2v[i]);
      writeY(yt); __syncthreads();
      feval(sf + C3f, k3v);
      #pragma unroll
      for (int i = 0; i < 4; ++i) yt[i] = y[i] + dvv * (A41f * k1v[i] + A42f * k2v[i] + A43f * k3v[i]);
      writeY(yt); __syncthreads();
      feval(sf + C4f, k4v);
      #pragma unroll
      for (int i = 0; i < 4; ++i) yt[i] = y[i] + dvv * (A51f * k1v[i] + A52f * k2v[i] + A53f * k3v[i] + A54f * k4v[i]);
      writeY(yt); __syncthreads();
      feval(sf + C5f, k5v);
      #pragma unroll
      for (int i = 0; i < 4; ++i) yt[i] = y[i] + dvv * (A61f * k1v[i] + A62f * k2v[i] + A63f * k3v[i] + A64f * k4v[i] + A65f * k5v[i]);
      writeY(yt); __syncthreads();
      feval(sf + C6f, k6v);
      #pragma unroll
      for (int i = 0; i < 4; ++i)
        y[i] += dvv * (B1f * k1v[i] + B2f * k2v[i] + B3f * k3v[i] + B4f * k4v[i] + B5f * k5v[i] + B6f * k6v[i]);
      writeY(y); __syncthreads();
    }

    // RNN: h = tanh(hp@wh.T + x@wx.T + bx); wh A-frags from LDS, wx from regs
    {
      f16x8 ha[4];
      #pragma unroll
      for (int kt = 0; kt < 4; ++kt) ha[kt] = *(const f16x8*)(lds + LDS_Y + ard + kt * 1024);
      f16x8 xa = *(const f16x8*)(lds + LDS_X + ard);
      f32x4 acc = {}, accb = {};
      __builtin_amdgcn_s_setprio(1);
      #pragma unroll
      for (int kt = 0; kt < 2; ++kt) {
        f16x8 bf  = *(const f16x8*)(lds + whrd + kt * 8192);
        f16x8 bf2 = *(const f16x8*)(lds + whrd + (kt + 2) * 8192);
        acc  = MFMA16(bf,  ha[kt],     acc);
        accb = MFMA16(bf2, ha[kt + 2], accb);
      }
      acc = MFMA16(WXf, xa, acc);
      __builtin_amdgcn_s_setprio(0);
      #pragma unroll
      for (int r = 0; r < 4; ++r) y[r] = tanh_fast(acc[r] + accb[r] + bxq[r]);
      writeY(y);
      __syncthreads();
    }
  }

  // ---------------- output head (swapped operands throughout) ----------------
  auto ldfrag2 = [](const float* p) {
    f16x8 v;
    #pragma unroll
    for (int j = 0; j < 8; ++j) v[j] = (f16)p[j];
    return v;
  };
  // H1: z = tanh(hN @ out_w0.T + out_b0)   K=128 -> 256 chans
  {
    f16x8 ha[4];
    #pragma unroll
    for (int kt = 0; kt < 4; ++kt) ha[kt] = *(const f16x8*)(lds + LDS_Y + ard + kt * 1024);
    f32x4 acc[2] = {};
    #pragma unroll
    for (int kt = 0; kt < 4; ++kt)
      #pragma unroll
      for (int nt = 0; nt < 2; ++nt) {
        f16x8 bf = ldfrag2(ow0g + (size_t)(c1 + nt * 16 + lr) * 128 + kt * 32 + lg * 8);
        acc[nt] = MFMA16(bf, ha[kt], acc[nt]);
      }
    #pragma unroll
    for (int nt = 0; nt < 2; ++nt) {
      const f32x4 bb = *(const f32x4*)(ob0g + c1 + nt * 16 + lg * 4);
      f16x4 p;
      #pragma unroll
      for (int r = 0; r < 4; ++r) p[r] = (f16)tanh_fast(acc[nt][r] + bb[r]);
      *(f16x4*)(lds + LDS_Z1 + w * 1024 + nt * 512 + awb) = p;
    }
  }
  __syncthreads();
  // H2: z = tanh(z @ out_w1.T + out_b1)   K=256 -> 256 chans
  {
    f16x8 za[8];
    #pragma unroll
    for (int kt = 0; kt < 8; ++kt) za[kt] = *(const f16x8*)(lds + LDS_Z1 + ard + kt * 1024);
    f32x4 acc[2] = {};
    #pragma unroll
    for (int kt = 0; kt < 8; ++kt)
      #pragma unroll
      for (int nt = 0; nt < 2; ++nt) {
        f16x8 bf = ldfrag2(ow1g + (size_t)(c1 + nt * 16 + lr) * 256 + kt * 32 + lg * 8);
        acc[nt] = MFMA16(bf, za[kt], acc[nt]);
      }
    #pragma unroll
    for (int nt = 0; nt < 2; ++nt) {
      const f32x4 bb = *(const f32x4*)(ob1g + c1 + nt * 16 + lg * 4);
      f16x4 p;
      #pragma unroll
      for (int r = 0; r < 4; ++r) p[r] = (f16)tanh_fast(acc[nt][r] + bb[r]);
      *(f16x4*)(lds + LDS_Z2 + w * 1024 + nt * 512 + awb) = p;
    }
  }
  __syncthreads();
  // H3: out = z @ out_w2.T + out_b2   K=256 -> 16 chans (wave 0 only)
  if (w == 0) {
    f16x8 za[8];
    #pragma unroll
    for (int kt = 0; kt < 8; ++kt) za[kt] = *(const f16x8*)(lds + LDS_Z2 + ard + kt * 1024);
    f32x4 acc = {};
    #pragma unroll
    for (int kt = 0; kt < 8; ++kt) {
      f16x8 bf = ldfrag2(ow2g + (size_t)lr * 256 + kt * 32 + lg * 8);
      acc = MFMA16(bf, za[kt], acc);
    }
    const f32x4 bb = *(const f32x4*)(ob2g + lg * 4);
    f32x4 vout;
    #pragma unroll
    for (int r = 0; r < 4; ++r) vout[r] = acc[r] + bb[r];
    *(f32x4*)(outg + (size_t)(rb + lr) * 16 + lg * 4) = vout;
  }
}

extern "C" void kernel_launch(void* const* d_in, const int* in_sizes, int n_in,
                              void* d_out, int out_size, void* d_ws, size_t ws_size,
                              hipStream_t stream) {
  (void)in_sizes; (void)n_in; (void)d_ws; (void)ws_size; (void)out_size;
  ode_rnn_kernel<<<dim3(8), dim3(512), 0, stream>>>(
      (const float*)d_in[0],  (const float*)d_in[1],  (const float*)d_in[2],
      (const float*)d_in[3],  (const float*)d_in[4],  (const float*)d_in[5],
      (const float*)d_in[6],  (const float*)d_in[7],  (const float*)d_in[8],
      (const float*)d_in[9],  (const float*)d_in[10], (const float*)d_in[11],
      (const float*)d_in[12], (const float*)d_in[13], (const float*)d_in[14],
      (const float*)d_in[15], (const float*)d_in[16], (const float*)d_in[17],
      (const float*)d_in[18], (const float*)d_in[19], (const float*)d_in[20],
      (float*)d_out);
}